// Round 6
// baseline (244.281 us; speedup 1.0000x reference)
//
#include <hip/hip_runtime.h>
#include <hip/hip_bf16.h>
#include <stdint.h>

typedef unsigned short u16;
typedef __bf16 bf16x8 __attribute__((ext_vector_type(8)));
typedef float f32x4 __attribute__((ext_vector_type(4)));
typedef unsigned short u16x4 __attribute__((ext_vector_type(4)));

#define BM 128
#define BN 128
#define BK 32

__device__ inline float bf2f(u16 v) {
    return __builtin_bit_cast(float, (uint32_t)v << 16);
}
__device__ inline u16 f2bf(float v) {
    return __builtin_bit_cast(u16, (__bf16)v);
}
__device__ inline void cvt_store8(u16* dst, float4 v) {
    u16x4 o;
    o[0] = f2bf(v.x); o[1] = f2bf(v.y); o[2] = f2bf(v.z); o[3] = f2bf(v.w);
    *reinterpret_cast<u16x4*>(dst) = o;
}
__device__ inline void gll16(const void* src, const char* lds_dst) {
    __builtin_amdgcn_global_load_lds(
        (const __attribute__((address_space(1))) void*)src,
        (__attribute__((address_space(3))) void*)lds_dst, 16, 0, 0);
}

// XCD-bijective remap (GEMM2 only): same-XCD dispatch chunk sweeps all by for
// consecutive bx, keeping the A-panel in that XCD's L2. total%8==0 holds.
__device__ inline void xcd_remap(int nby, int& bx, int& by) {
    const int lin = (int)blockIdx.x + (int)blockIdx.y * (int)gridDim.x;
    const int g = lin & 7, s = lin >> 3;
    by = s % nby;
    bx = (s / nby) * 8 + g;
}

// ---------------------------------------------------------------------------
// T2 LDS swizzle, 2-bit involution (BK=32 u16 -> 4 granules of 16B per row):
//   LDS (row, g) <- global (row, g ^ ((row>>1)&3))
// Closed over g in 0..3 (round-5 bug: 3-bit XOR escaped the row slot).
// Staging rows step by +32/+64 and fragment rows by +16 -> (row>>1)&3
// invariant, so one per-thread XOR works for all rounds/fragments.
// Bank math: lanes 0..15 at fixed cg hit slot (r&1)*4 + (cg^((r>>1)&3)) =
// 8 distinct 16B slots x 2 lanes = 2-way = free.
// ---------------------------------------------------------------------------

// ---------------------------------------------------------------------------
// GEMM1 fused + split-K: P[bz][M][N](f32) = A[M][Kh](f32, cvt in staging)
//                                           @ Bt[N][Kh]^T(bf16)
// grid (4=by, 128=bx, 2=bz). Double-buffered LDS, one barrier per K-step.
// A: reg-staged f32->bf16 with swizzled ds_write; B: gll16 w/ swizzled source.
// ---------------------------------------------------------------------------
__global__ __launch_bounds__(256) void gemm_xf32_bt_sk(
    const float* __restrict__ A, const u16* __restrict__ Bt,
    float* __restrict__ P, int M, int N, int K)
{
    __shared__ u16 Al[2][BM * BK];
    __shared__ u16 Bl[2][BN * BK];
    const int by = (int)blockIdx.x;
    const int bx = (int)blockIdx.y;
    const int bz = (int)blockIdx.z;
    const int KH = K >> 1;
    const int kbase = bz * KH;

    const int tid  = threadIdx.x;
    const int wave = tid >> 6;
    const int lane = tid & 63;
    const int wr   = wave >> 1;
    const int wc   = wave & 1;

    // B staging: thread t -> linear LDS slot t (row=t>>2, granule=t&3);
    // source granule pre-swizzled: (t&3) ^ ((row>>1)&3), row>>1 = t>>3
    const int srow = tid >> 2;
    const int skk  = (((tid & 3) ^ ((tid >> 3) & 3)) << 3);
    const u16* bbase0 = Bt + (long)(by * BN + srow) * K + kbase + skk;
    const u16* bbase1 = bbase0 + (long)64 * K;
    char* blds = (char*)&Bl[0][0];
    const int wslot = wave * 1024;

    // A reg-staging: 4 float4/thread; round r covers rows arow + r*32
    // ((row>>1)&3 invariant). ds_write address carries the XOR.
    const int arow = tid >> 3;         // 0..31
    const int akk  = (tid & 7) * 4;    // natural k-elems [akk, akk+4)
    const float* abase = A + (long)(bx * BM + arow) * K + kbase + akk;
    const long arstr = (long)32 * K;
    const int awoff = arow * BK
        + (((akk >> 3) ^ ((arow >> 1) & 3)) << 3) + (akk & 7);

    f32x4 acc[4][4];
#pragma unroll
    for (int i = 0; i < 4; ++i)
#pragma unroll
        for (int j = 0; j < 4; ++j) acc[i][j] = (f32x4){0.f, 0.f, 0.f, 0.f};

    // fragment reads: row = (wr|wc)*64 + fr + m*16; want global granule
    // cg=lane>>4 -> read LDS granule cg ^ ((fr>>1)&3)
    const int fr  = lane & 15;
    const int cg  = lane >> 4;
    const int swz = ((cg ^ ((fr >> 1) & 3)) << 3);
    const int aoff = (wr * 64 + fr) * BK + swz;
    const int boff = (wc * 64 + fr) * BK + swz;

    const int NT = KH / BK;   // 32

    // prologue: stage tile 0 into buffer 0
    {
        gll16(bbase0, blds + wslot);
        gll16(bbase1, blds + 4096 + wslot);
        float4 p0 = *(const float4*)(abase);
        float4 p1 = *(const float4*)(abase + arstr);
        float4 p2 = *(const float4*)(abase + 2 * arstr);
        float4 p3 = *(const float4*)(abase + 3 * arstr);
        cvt_store8(&Al[0][awoff + 0 * 32 * BK], p0);
        cvt_store8(&Al[0][awoff + 1 * 32 * BK], p1);
        cvt_store8(&Al[0][awoff + 2 * 32 * BK], p2);
        cvt_store8(&Al[0][awoff + 3 * 32 * BK], p3);
        __syncthreads();
    }

    for (int t = 0; t < NT; ++t) {
        const int cur = t & 1, nxt = cur ^ 1;
        const int ktn = (t + 1 < NT) ? (t + 1) * BK : 0;  // clamped, never read

        // issue next A loads (consumed after MFMA)
        const float* an = abase + ktn;
        float4 p0 = *(const float4*)(an);
        float4 p1 = *(const float4*)(an + arstr);
        float4 p2 = *(const float4*)(an + 2 * arstr);
        float4 p3 = *(const float4*)(an + 3 * arstr);
        // issue next B staging into the other buffer
        gll16(bbase0 + ktn, blds + nxt * 8192 + wslot);
        gll16(bbase1 + ktn, blds + nxt * 8192 + 4096 + wslot);

        bf16x8 af[4], bfg[4];
#pragma unroll
        for (int m = 0; m < 4; ++m)
            af[m] = *(const bf16x8*)&Al[cur][aoff + m * 16 * BK];
#pragma unroll
        for (int n = 0; n < 4; ++n)
            bfg[n] = *(const bf16x8*)&Bl[cur][boff + n * 16 * BK];
#pragma unroll
        for (int m = 0; m < 4; ++m)
#pragma unroll
            for (int n = 0; n < 4; ++n)
                acc[m][n] = __builtin_amdgcn_mfma_f32_16x16x32_bf16(
                    af[m], bfg[n], acc[m][n], 0, 0, 0);

        cvt_store8(&Al[nxt][awoff + 0 * 32 * BK], p0);
        cvt_store8(&Al[nxt][awoff + 1 * 32 * BK], p1);
        cvt_store8(&Al[nxt][awoff + 2 * 32 * BK], p2);
        cvt_store8(&Al[nxt][awoff + 3 * 32 * BK], p3);
        __syncthreads();
    }

    float* Pz = P + (long)bz * M * N;
    const int crow = bx * BM + wr * 64 + (lane >> 4) * 4;
    const int ccol = by * BN + wc * 64 + (lane & 15);
#pragma unroll
    for (int m = 0; m < 4; ++m)
#pragma unroll
        for (int n = 0; n < 4; ++n)
#pragma unroll
            for (int j = 0; j < 4; ++j)
                Pz[(long)(crow + m * 16 + j) * N + (ccol + n * 16)] = acc[m][n][j];
}

// ---------------------------------------------------------------------------
// GEMM2: C[M][N](f32) = A[M][K](bf16) @ Bt[N][K]^T(bf16)
// Double-buffered LDS, one barrier per K-step, gll16 w/ swizzled sources.
// ---------------------------------------------------------------------------
__global__ __launch_bounds__(256) void gemm_bt(
    const u16* __restrict__ A, const u16* __restrict__ Bt,
    float* __restrict__ C, int M, int N, int K)
{
    __shared__ u16 Al[2][BM * BK];
    __shared__ u16 Bl[2][BN * BK];
    int bx, by; xcd_remap((int)gridDim.y, bx, by);

    const int tid  = threadIdx.x;
    const int wave = tid >> 6;
    const int lane = tid & 63;
    const int wr   = wave >> 1;
    const int wc   = wave & 1;

    const int srow = tid >> 2;
    const int skk  = (((tid & 3) ^ ((tid >> 3) & 3)) << 3);

    const u16* abase0 = A + (long)(bx * BM + srow) * K + skk;
    const u16* abase1 = abase0 + (long)64 * K;
    const u16* bbase0 = Bt + (long)(by * BN + srow) * K + skk;
    const u16* bbase1 = bbase0 + (long)64 * K;

    char* alds = (char*)&Al[0][0];
    char* blds = (char*)&Bl[0][0];
    const int wslot = wave * 1024;

    f32x4 acc[4][4];
#pragma unroll
    for (int i = 0; i < 4; ++i)
#pragma unroll
        for (int j = 0; j < 4; ++j) acc[i][j] = (f32x4){0.f, 0.f, 0.f, 0.f};

    const int fr  = lane & 15;
    const int cg  = lane >> 4;
    const int swz = ((cg ^ ((fr >> 1) & 3)) << 3);
    const int aoff = (wr * 64 + fr) * BK + swz;
    const int boff = (wc * 64 + fr) * BK + swz;

    const int NT = K / BK;

    gll16(abase0, alds + wslot);
    gll16(abase1, alds + 4096 + wslot);
    gll16(bbase0, blds + wslot);
    gll16(bbase1, blds + 4096 + wslot);
    __syncthreads();

    for (int t = 0; t < NT; ++t) {
        const int cur = t & 1, nxt = cur ^ 1;
        const int ktn = (t + 1 < NT) ? (t + 1) * BK : 0;

        gll16(abase0 + ktn, alds + nxt * 8192 + wslot);
        gll16(abase1 + ktn, alds + nxt * 8192 + 4096 + wslot);
        gll16(bbase0 + ktn, blds + nxt * 8192 + wslot);
        gll16(bbase1 + ktn, blds + nxt * 8192 + 4096 + wslot);

        bf16x8 af[4], bfg[4];
#pragma unroll
        for (int m = 0; m < 4; ++m)
            af[m] = *(const bf16x8*)&Al[cur][aoff + m * 16 * BK];
#pragma unroll
        for (int n = 0; n < 4; ++n)
            bfg[n] = *(const bf16x8*)&Bl[cur][boff + n * 16 * BK];
#pragma unroll
        for (int m = 0; m < 4; ++m)
#pragma unroll
            for (int n = 0; n < 4; ++n)
                acc[m][n] = __builtin_amdgcn_mfma_f32_16x16x32_bf16(
                    af[m], bfg[n], acc[m][n], 0, 0, 0);

        __syncthreads();
    }

    const int crow = bx * BM + wr * 64 + (lane >> 4) * 4;
    const int ccol = by * BN + wc * 64 + (lane & 15);
#pragma unroll
    for (int m = 0; m < 4; ++m)
#pragma unroll
        for (int n = 0; n < 4; ++n)
#pragma unroll
            for (int j = 0; j < 4; ++j)
                C[(long)(crow + m * 16 + j) * N + (ccol + n * 16)] = acc[m][n][j];
}

// ---------------------------------------------------------------------------
// fused 3-layer EMA scan; input h = P0 + P1 (f32 split-K partials).
// SCHUNK=64, LOOK=256; double-buffered 8-deep register prefetch.
// ---------------------------------------------------------------------------
#define SCHUNK 64
#define SLOOK  256

__device__ inline float sigmoidf_(float x) { return 1.f / (1.f + __expf(-x)); }

__global__ __launch_bounds__(256) void ema3_scan_f32x2(
    const float* __restrict__ P0, const float* __restrict__ P1,
    const float* __restrict__ log_a, u16* __restrict__ h3)
{
    const int t = (int)blockIdx.x * 256 + (int)threadIdx.x;  // 131072 threads
    const int e     = t & 511;
    const int b     = (t >> 9) & 3;
    const int chunk = t >> 11;           // 0..63
    const float a1 = sigmoidf_(log_a[e]);
    const float a2 = sigmoidf_(log_a[512 + e]);
    const float a3 = sigmoidf_(log_a[1024 + e]);
    const float c1 = 1.f - a1, c2 = 1.f - a2, c3 = 1.f - a3;
    const long base = ((long)b * 4096) * 512 + e;
    const int l0 = chunk * SCHUNK;
    const int ls = (l0 - SLOOK > 0) ? (l0 - SLOOK) : 0;
    const int S  = l0 + SCHUNK - ls;     // 64..320, all /16
    const float* p0 = P0 + base + (long)ls * 512;
    const float* p1 = P1 + base + (long)ls * 512;
    u16* op = h3 + base + (long)ls * 512;
    int gl = ls;
    float y1 = 0.f, y2 = 0.f, y3 = 0.f;

    float A0[8], A1[8], B0[8], B1[8];
#pragma unroll
    for (int i = 0; i < 8; ++i) { A0[i] = p0[(long)i * 512]; A1[i] = p1[(long)i * 512]; }
    p0 += 8 * 512; p1 += 8 * 512;

    const int nb = S >> 4;
    for (int ib = 0; ib < nb; ++ib) {
#pragma unroll
        for (int i = 0; i < 8; ++i) { B0[i] = p0[(long)i * 512]; B1[i] = p1[(long)i * 512]; }
        p0 += 8 * 512; p1 += 8 * 512;
#pragma unroll
        for (int i = 0; i < 8; ++i) {
            const float v = A0[i] + A1[i];
            y1 = a1 * y1 + c1 * v;
            y2 = a2 * y2 + c2 * y1;
            y3 = a3 * y3 + c3 * y2;
            if (gl >= l0) *op = f2bf(y3);
            op += 512; ++gl;
        }
        // over-reads up to 8 rows past chunk end — stays inside the 128MiB
        // d_out region (P0 at +0, P1 at +32MiB); values never consumed.
#pragma unroll
        for (int i = 0; i < 8; ++i) { A0[i] = p0[(long)i * 512]; A1[i] = p1[(long)i * 512]; }
        p0 += 8 * 512; p1 += 8 * 512;
#pragma unroll
        for (int i = 0; i < 8; ++i) {
            const float v = B0[i] + B1[i];
            y1 = a1 * y1 + c1 * v;
            y2 = a2 * y2 + c2 * y1;
            y3 = a3 * y3 + c3 * y2;
            if (gl >= l0) *op = f2bf(y3);
            op += 512; ++gl;
        }
    }
}

// ---------------------------------------------------------------------------
// both weight matrices f32 -> bf16 in one launch (1M f32 each)
// ---------------------------------------------------------------------------
__global__ __launch_bounds__(256) void cvt_weights(
    const float* __restrict__ wd, const float* __restrict__ wu,
    u16* __restrict__ wd_o, u16* __restrict__ wu_o, int n4each)
{
    int i = (int)blockIdx.x * 256 + (int)threadIdx.x;
    const int stride = (int)gridDim.x * 256;
    for (; i < 2 * n4each; i += stride) {
        const float* in = (i < n4each) ? wd : wu;
        u16* out = (i < n4each) ? wd_o : wu_o;
        const int j = (i < n4each) ? i : (i - n4each);
        const float4 v = reinterpret_cast<const float4*>(in)[j];
        u16x4 o;
        o[0] = f2bf(v.x); o[1] = f2bf(v.y); o[2] = f2bf(v.z); o[3] = f2bf(v.w);
        reinterpret_cast<u16x4*>(out)[j] = o;
    }
}

// ---------------------------------------------------------------------------
// B=4, L=4096, D=2048, Di=512. Scratch plan:
//   d_out[0:32MiB)   = P0 (f32 split-K partial)   } dead before GEMM2
//   d_out[32:64MiB)  = P1 (f32 split-K partial)   } overwrites d_out
//   d_ws[0:2MiB)     = W_down bf16
//   d_ws[2:4MiB)     = W_up   bf16
//   d_ws[4:20MiB)    = h3 bf16
// ---------------------------------------------------------------------------
extern "C" void kernel_launch(void* const* d_in, const int* in_sizes, int n_in,
                              void* d_out, int out_size, void* d_ws, size_t ws_size,
                              hipStream_t stream)
{
    const float* x      = (const float*)d_in[0];
    const float* W_down = (const float*)d_in[1];
    const float* W_up   = (const float*)d_in[2];
    const float* log_a  = (const float*)d_in[3];
    float* out = (float*)d_out;

    float* P0    = (float*)d_out;
    float* P1    = (float*)((char*)d_out + (32u << 20));
    u16*   Wd_bf = (u16*)d_ws;
    u16*   Wu_bf = (u16*)((char*)d_ws + (2u << 20));
    u16*   h3    = (u16*)((char*)d_ws + (4u << 20));

    cvt_weights<<<512, 256, 0, stream>>>(W_down, W_up, Wd_bf, Wu_bf,
                                         (512 * 2048) / 4);

    // P[bz] = x @ W_down^T (per K-half)  (M=16384, N=512, K=2048)
    gemm_xf32_bt_sk<<<dim3(4, 128, 2), 256, 0, stream>>>(
        x, Wd_bf, P0, 16384, 512, 2048);

    // 3-layer EMA scan on P0+P1, bf16 out
    ema3_scan_f32x2<<<512, 256, 0, stream>>>(P0, P1, log_a, h3);

    // out = h3 @ W_up^T  (M=16384, N=2048, K=512), f32 out
    gemm_bt<<<dim3(128, 16), 256, 0, stream>>>(h3, Wu_bf, out, 16384, 2048, 512);
}

// Round 8
// 173.199 us; speedup vs baseline: 1.4104x; 1.4104x over previous
//
#include <hip/hip_runtime.h>
#include <hip/hip_bf16.h>
#include <stdint.h>

typedef unsigned short u16;
typedef __bf16 bf16x8 __attribute__((ext_vector_type(8)));
typedef float f32x4 __attribute__((ext_vector_type(4)));
typedef unsigned short u16x4 __attribute__((ext_vector_type(4)));

#define BM 128
#define BN 128
#define BK 32

__device__ inline float bf2f(u16 v) {
    return __builtin_bit_cast(float, (uint32_t)v << 16);
}
__device__ inline u16 f2bf(float v) {
    return __builtin_bit_cast(u16, (__bf16)v);
}
__device__ inline void gll16(const void* src, const char* lds_dst) {
    __builtin_amdgcn_global_load_lds(
        (const __attribute__((address_space(1))) void*)src,
        (__attribute__((address_space(3))) void*)lds_dst, 16, 0, 0);
}

// XCD-bijective remap. CONVENTION (R7 post-mortem): nby MUST be the number
// of N-tiles and the launch MUST be dim3(n_M_tiles, n_N_tiles) so that
// nby == gridDim.y. by = N-tile in [0,nby), bx = M-tile. Same-XCD dispatch
// chunk sweeps all by for consecutive bx (A-panel stays in that XCD's L2).
__device__ inline void xcd_remap(int nby, int& bx, int& by) {
    const int lin = (int)blockIdx.x + (int)blockIdx.y * (int)gridDim.x;
    const int g = lin & 7, s = lin >> 3;
    by = s % nby;
    bx = (s / nby) * 8 + g;
}

// ---------------------------------------------------------------------------
// LDS swizzles (16B granules, involution closed over the per-row granule
// count — round-5 lesson):
//   bf16 tile [128][32]: 4 granules/row, g' = g ^ ((row>>1)&3)   (R6-verified)
//   f32  tile [128][32]: 8 granules/row, g' = g ^ (row&7)
// Staging rows step by +32/+64 and fragment rows by +16, so the row-XOR bits
// are invariant per thread; sources are pre-swizzled, reads XOR the granule
// (rule #21: same involution both sides, LDS dest linear).
// ---------------------------------------------------------------------------

// ---------------------------------------------------------------------------
// GEMM1: h[M][N](bf16) = x[M][K](f32) @ Wd[N][K]^T(bf16)
// m97 single-buffer structure; A staged RAW f32 via gll16 (4 rounds),
// converted to bf16 at fragment read (2x ds_read_b128 + 8 cvt per frag).
// ---------------------------------------------------------------------------
__global__ __launch_bounds__(256) void gemm_xf32lds(
    const float* __restrict__ A, const u16* __restrict__ Bt,
    u16* __restrict__ C, int M, int N, int K)
{
    __shared__ float Af[BM * BK];   // 16 KiB
    __shared__ u16   Bl[BN * BK];   //  8 KiB
    int bx, by; xcd_remap((int)gridDim.y, bx, by);

    const int tid  = threadIdx.x;
    const int wave = tid >> 6;
    const int lane = tid & 63;
    const int wr   = wave >> 1;
    const int wc   = wave & 1;

    // A staging: 4 rounds; round r covers rows r*32 + (t>>3); thread t owns
    // granule (t&7), source granule pre-swizzled with row&7 = (t>>3)&7.
    const int ag = (tid & 7) ^ ((tid >> 3) & 7);
    const float* abase = A + (long)(bx * BM + (tid >> 3)) * K + ag * 4;
    char* aldsb = (char*)&Af[0];
    // B staging: 2 rounds; row = r*64 + (t>>2); source granule
    // (t&3) ^ ((row>>1)&3), (row>>1)&3 = (t>>3)&3.
    const int srow = tid >> 2;
    const int skk  = (((tid & 3) ^ ((tid >> 3) & 3)) << 3);
    const u16* bbase0 = Bt + (long)(by * BN + srow) * K + skk;
    const u16* bbase1 = bbase0 + (long)64 * K;
    char* blds = (char*)&Bl[0];
    const int wslot = wave * 1024;

    f32x4 acc[4][4];
#pragma unroll
    for (int i = 0; i < 4; ++i)
#pragma unroll
        for (int j = 0; j < 4; ++j) acc[i][j] = (f32x4){0.f, 0.f, 0.f, 0.f};

    // fragment maps
    const int fr  = lane & 15;
    const int rx7 = fr & 7;                 // f32-A row XOR (3-bit)
    const int gn0 = (lane >> 4) * 2;        // f32-A natural granules gn0,gn0+1
    const int cgB = lane >> 4;              // bf16-B granule
    const int swzB = ((cgB ^ ((fr >> 1) & 3)) << 3);
    const int boff = (wc * 64 + fr) * BK + swzB;
    const int arow0 = wr * 64 + fr;

    for (int kt = 0; kt < K; kt += BK) {
        // stage A (f32, 4 rounds) + B (bf16, 2 rounds)
        gll16(abase + kt,                aldsb + 0 * 4096 + wslot);
        gll16(abase + kt + (long)32 * K, aldsb + 1 * 4096 + wslot);
        gll16(abase + kt + (long)64 * K, aldsb + 2 * 4096 + wslot);
        gll16(abase + kt + (long)96 * K, aldsb + 3 * 4096 + wslot);
        gll16(bbase0 + kt, blds + wslot);
        gll16(bbase1 + kt, blds + 4096 + wslot);
        __syncthreads();   // drain vmcnt -> tile visible

        bf16x8 af[4], bfg[4];
#pragma unroll
        for (int m = 0; m < 4; ++m) {
            const int row = arow0 + m * 16;
            const f32x4 alo = *(const f32x4*)&Af[row * BK + (((gn0)     ^ rx7) << 2)];
            const f32x4 ahi = *(const f32x4*)&Af[row * BK + (((gn0 + 1) ^ rx7) << 2)];
            af[m][0] = (__bf16)alo[0]; af[m][1] = (__bf16)alo[1];
            af[m][2] = (__bf16)alo[2]; af[m][3] = (__bf16)alo[3];
            af[m][4] = (__bf16)ahi[0]; af[m][5] = (__bf16)ahi[1];
            af[m][6] = (__bf16)ahi[2]; af[m][7] = (__bf16)ahi[3];
        }
#pragma unroll
        for (int n = 0; n < 4; ++n)
            bfg[n] = *(const bf16x8*)&Bl[boff + n * 16 * BK];
#pragma unroll
        for (int m = 0; m < 4; ++m)
#pragma unroll
            for (int n = 0; n < 4; ++n)
                acc[m][n] = __builtin_amdgcn_mfma_f32_16x16x32_bf16(
                    af[m], bfg[n], acc[m][n], 0, 0, 0);
        __syncthreads();   // reads done before next stage overwrites
    }

    const int crow = bx * BM + wr * 64 + (lane >> 4) * 4;
    const int ccol = by * BN + wc * 64 + (lane & 15);
#pragma unroll
    for (int m = 0; m < 4; ++m)
#pragma unroll
        for (int n = 0; n < 4; ++n)
#pragma unroll
            for (int j = 0; j < 4; ++j)
                C[(long)(crow + m * 16 + j) * N + (ccol + n * 16)] =
                    f2bf(acc[m][n][j]);
}

// ---------------------------------------------------------------------------
// GEMM2: C[M][N](f32) = A[M][K](bf16) @ Bt[N][K]^T(bf16)
// m97 single-buffer + gll16 both operands, swizzled, XCD remap.
// ---------------------------------------------------------------------------
__global__ __launch_bounds__(256) void gemm_bt(
    const u16* __restrict__ A, const u16* __restrict__ Bt,
    float* __restrict__ C, int M, int N, int K)
{
    __shared__ u16 Al[BM * BK];
    __shared__ u16 Bl[BN * BK];
    int bx, by; xcd_remap((int)gridDim.y, bx, by);

    const int tid  = threadIdx.x;
    const int wave = tid >> 6;
    const int lane = tid & 63;
    const int wr   = wave >> 1;
    const int wc   = wave & 1;

    const int srow = tid >> 2;
    const int skk  = (((tid & 3) ^ ((tid >> 3) & 3)) << 3);

    const u16* abase0 = A + (long)(bx * BM + srow) * K + skk;
    const u16* abase1 = abase0 + (long)64 * K;
    const u16* bbase0 = Bt + (long)(by * BN + srow) * K + skk;
    const u16* bbase1 = bbase0 + (long)64 * K;

    char* alds = (char*)&Al[0];
    char* blds = (char*)&Bl[0];
    const int wslot = wave * 1024;

    f32x4 acc[4][4];
#pragma unroll
    for (int i = 0; i < 4; ++i)
#pragma unroll
        for (int j = 0; j < 4; ++j) acc[i][j] = (f32x4){0.f, 0.f, 0.f, 0.f};

    const int fr  = lane & 15;
    const int cg  = lane >> 4;
    const int swz = ((cg ^ ((fr >> 1) & 3)) << 3);
    const int aoff = (wr * 64 + fr) * BK + swz;
    const int boff = (wc * 64 + fr) * BK + swz;

    for (int kt = 0; kt < K; kt += BK) {
        gll16(abase0 + kt, alds + wslot);
        gll16(abase1 + kt, alds + 4096 + wslot);
        gll16(bbase0 + kt, blds + wslot);
        gll16(bbase1 + kt, blds + 4096 + wslot);
        __syncthreads();

        bf16x8 af[4], bfg[4];
#pragma unroll
        for (int m = 0; m < 4; ++m)
            af[m] = *(const bf16x8*)&Al[aoff + m * 16 * BK];
#pragma unroll
        for (int n = 0; n < 4; ++n)
            bfg[n] = *(const bf16x8*)&Bl[boff + n * 16 * BK];
#pragma unroll
        for (int m = 0; m < 4; ++m)
#pragma unroll
            for (int n = 0; n < 4; ++n)
                acc[m][n] = __builtin_amdgcn_mfma_f32_16x16x32_bf16(
                    af[m], bfg[n], acc[m][n], 0, 0, 0);
        __syncthreads();
    }

    const int crow = bx * BM + wr * 64 + (lane >> 4) * 4;
    const int ccol = by * BN + wc * 64 + (lane & 15);
#pragma unroll
    for (int m = 0; m < 4; ++m)
#pragma unroll
        for (int n = 0; n < 4; ++n)
#pragma unroll
            for (int j = 0; j < 4; ++j)
                C[(long)(crow + m * 16 + j) * N + (ccol + n * 16)] = acc[m][n][j];
}

// ---------------------------------------------------------------------------
// fused 3-layer EMA scan (R2-verified): bf16 in/out, SCHUNK=128, LOOK=256,
// double-buffered 8-deep register prefetch.
// ---------------------------------------------------------------------------
#define SCHUNK 128
#define SLOOK  256

__device__ inline float sigmoidf_(float x) { return 1.f / (1.f + __expf(-x)); }

__global__ __launch_bounds__(256) void ema3_scan_bf(
    const u16* __restrict__ h, const float* __restrict__ log_a,
    u16* __restrict__ h3)
{
    const int t = (int)blockIdx.x * 256 + (int)threadIdx.x;  // 65536 threads
    const int e     = t & 511;
    const int b     = (t >> 9) & 3;
    const int chunk = t >> 11;           // 0..31
    const float a1 = sigmoidf_(log_a[e]);
    const float a2 = sigmoidf_(log_a[512 + e]);
    const float a3 = sigmoidf_(log_a[1024 + e]);
    const float c1 = 1.f - a1, c2 = 1.f - a2, c3 = 1.f - a3;
    const long base = ((long)b * 4096) * 512 + e;
    const int l0 = chunk * SCHUNK;
    const int ls = (l0 - SLOOK > 0) ? (l0 - SLOOK) : 0;
    const int S  = l0 + SCHUNK - ls;     // 128 / 256 / 384 — all /16
    const u16* hp = h + base + (long)ls * 512;
    u16* op = h3 + base + (long)ls * 512;
    int gl = ls;
    float y1 = 0.f, y2 = 0.f, y3 = 0.f;

    u16 A[8], B[8];
#pragma unroll
    for (int i = 0; i < 8; ++i) A[i] = hp[(long)i * 512];
    hp += 8 * 512;

    const int nb = S >> 4;
    for (int ib = 0; ib < nb; ++ib) {
#pragma unroll
        for (int i = 0; i < 8; ++i) B[i] = hp[(long)i * 512];
        hp += 8 * 512;
#pragma unroll
        for (int i = 0; i < 8; ++i) {
            const float v = bf2f(A[i]);
            y1 = a1 * y1 + c1 * v;
            y2 = a2 * y2 + c2 * y1;
            y3 = a3 * y3 + c3 * y2;
            if (gl >= l0) *op = f2bf(y3);
            op += 512; ++gl;
        }
        // over-reads up to 8 rows past chunk end (in-bounds: h sits at
        // d_out+64MiB inside the 128MiB region; values never consumed)
#pragma unroll
        for (int i = 0; i < 8; ++i) A[i] = hp[(long)i * 512];
        hp += 8 * 512;
#pragma unroll
        for (int i = 0; i < 8; ++i) {
            const float v = bf2f(B[i]);
            y1 = a1 * y1 + c1 * v;
            y2 = a2 * y2 + c2 * y1;
            y3 = a3 * y3 + c3 * y2;
            if (gl >= l0) *op = f2bf(y3);
            op += 512; ++gl;
        }
    }
}

// ---------------------------------------------------------------------------
// both weight matrices f32 -> bf16 in one launch (1M f32 each)
// ---------------------------------------------------------------------------
__global__ __launch_bounds__(256) void cvt_weights(
    const float* __restrict__ wd, const float* __restrict__ wu,
    u16* __restrict__ wd_o, u16* __restrict__ wu_o, int n4each)
{
    int i = (int)blockIdx.x * 256 + (int)threadIdx.x;
    const int stride = (int)gridDim.x * 256;
    for (; i < 2 * n4each; i += stride) {
        const float* in = (i < n4each) ? wd : wu;
        u16* out = (i < n4each) ? wd_o : wu_o;
        const int j = (i < n4each) ? i : (i - n4each);
        const float4 v = reinterpret_cast<const float4*>(in)[j];
        u16x4 o;
        o[0] = f2bf(v.x); o[1] = f2bf(v.y); o[2] = f2bf(v.z); o[3] = f2bf(v.w);
        reinterpret_cast<u16x4*>(out)[j] = o;
    }
}

// ---------------------------------------------------------------------------
// B=4, L=4096, D=2048, Di=512. Scratch plan:
//   d_out[64:80MiB)  = h (bf16)   (dead before GEMM2 overwrites d_out)
//   d_ws[0:2MiB)     = W_down bf16
//   d_ws[2:4MiB)     = W_up   bf16
//   d_ws[4:20MiB)    = h3 bf16
// ---------------------------------------------------------------------------
extern "C" void kernel_launch(void* const* d_in, const int* in_sizes, int n_in,
                              void* d_out, int out_size, void* d_ws, size_t ws_size,
                              hipStream_t stream)
{
    const float* x      = (const float*)d_in[0];
    const float* W_down = (const float*)d_in[1];
    const float* W_up   = (const float*)d_in[2];
    const float* log_a  = (const float*)d_in[3];
    float* out = (float*)d_out;

    u16*   h_bf  = (u16*)((char*)d_out + (64u << 20));
    u16*   Wd_bf = (u16*)d_ws;
    u16*   Wu_bf = (u16*)((char*)d_ws + (2u << 20));
    u16*   h3    = (u16*)((char*)d_ws + (4u << 20));

    cvt_weights<<<512, 256, 0, stream>>>(W_down, W_up, Wd_bf, Wu_bf,
                                         (512 * 2048) / 4);

    // h = x @ W_down^T   (M=16384, N=512, K=2048)
    // grid = dim3(n_M_tiles=128, n_N_tiles=4)  [xcd_remap convention]
    gemm_xf32lds<<<dim3(128, 4), 256, 0, stream>>>(x, Wd_bf, h_bf, 16384, 512, 2048);

    // 3-layer EMA scan, bf16 in/out
    ema3_scan_bf<<<256, 256, 0, stream>>>(h_bf, log_a, h3);

    // out = h3 @ W_up^T  (M=16384, N=2048, K=512)
    // grid = dim3(n_M_tiles=128, n_N_tiles=16)
    gemm_bt<<<dim3(128, 16), 256, 0, stream>>>(h3, Wu_bf, out, 16384, 2048, 512);
}